// Round 9
// baseline (556.061 us; speedup 1.0000x reference)
//
#include <hip/hip_runtime.h>
#include <hip/hip_bf16.h>

#define VOCAB 50257
#define EMBED 128
#define BATCH 4096
#define CTX   8

#define BM 128
#define NXT 786            // 64-col strips
#define VPAD 50304
#define LDSP 136

#define BANDS   64         // 4096 rows / 64-row bands
#define QCHUNKS 99         // ceil(786/8) 8-strip col chunks
#define NTICK (BANDS * QCHUNKS)   // 6336 tickets

typedef __attribute__((ext_vector_type(8))) short bf16x8;
typedef __attribute__((ext_vector_type(4))) float f32x4;
typedef float f32x4u __attribute__((ext_vector_type(4), aligned(4)));

static __device__ __forceinline__ ushort f2bf(float f) {
  __hip_bfloat16 h = __float2bfloat16(f);
  return *reinterpret_cast<ushort*>(&h);
}

// ---------------- Kernel 1: embedding bag -> bf16 word_emb ----------------
__global__ __launch_bounds__(256) void embed_bag_kernel(
    const int* __restrict__ idx, const float* __restrict__ Wp,
    __hip_bfloat16* __restrict__ emb) {
  int wave = threadIdx.x >> 6;
  int lane = threadIdx.x & 63;
  int row  = blockIdx.x * 4 + wave;
  const int* ri = idx + row * CTX;
  int e0 = lane * 2;
  float s0 = 0.f, s1 = 0.f;
#pragma unroll
  for (int c = 0; c < CTX; ++c) {
    int w = ri[c];
    float2 wv = *reinterpret_cast<const float2*>(Wp + (size_t)w * EMBED + e0);
    s0 += wv.x; s1 += wv.y;
  }
  __hip_bfloat162 pv;
  pv.x = __float2bfloat16(s0);
  pv.y = __float2bfloat16(s1);
  *reinterpret_cast<__hip_bfloat162*>(emb + (size_t)row * EMBED + e0) = pv;
}

// ------- Kernel 1b: W_pred [128][50257]f32 -> Btf fragment-ordered bf16 -------
// Btf[strip][instr=kq*4+n][lane][8]: lane reads exactly its MFMA B-fragment.
__global__ __launch_bounds__(256) void transpose_b_kernel(
    const float* __restrict__ Bm, ushort* __restrict__ Btf) {
  __shared__ ushort Bs[64 * LDSP];
  int x = blockIdx.x;
  int cbase = x * 64;
  int tid = threadIdx.x;
  bool edge = (cbase + 64 > VOCAB);
#pragma unroll
  for (int i = 0; i < 8; ++i) {
    int c  = tid + i * 256;
    int e  = c >> 4;
    int v4 = (c & 15) << 2;
    int col = cbase + v4;
    float4 b;
    if (!edge) {
      b = *reinterpret_cast<const float4*>(Bm + (size_t)e * VOCAB + col);
    } else {
      b.x = (col + 0 < VOCAB) ? Bm[(size_t)e * VOCAB + col + 0] : 0.f;
      b.y = (col + 1 < VOCAB) ? Bm[(size_t)e * VOCAB + col + 1] : 0.f;
      b.z = (col + 2 < VOCAB) ? Bm[(size_t)e * VOCAB + col + 2] : 0.f;
      b.w = (col + 3 < VOCAB) ? Bm[(size_t)e * VOCAB + col + 3] : 0.f;
    }
    Bs[(v4 + 0) * LDSP + e] = f2bf(b.x);
    Bs[(v4 + 1) * LDSP + e] = f2bf(b.y);
    Bs[(v4 + 2) * LDSP + e] = f2bf(b.z);
    Bs[(v4 + 3) * LDSP + e] = f2bf(b.w);
  }
  __syncthreads();
  int lane = tid & 63, wv = tid >> 6;
  int lr = lane & 15, lg = lane >> 4;
#pragma unroll
  for (int p = 0; p < 4; ++p) {
    int instr = p * 4 + wv;
    int kq = instr >> 2, n = instr & 3;
    int v  = n * 16 + lr;
    int e0 = kq * 32 + lg * 8;
    uint4 val = *reinterpret_cast<const uint4*>(&Bs[v * LDSP + e0]);
    *reinterpret_cast<uint4*>(Btf + (size_t)x * 8192 + instr * 512 + lane * 8) = val;
  }
}

// ------ Kernel 2: ordered-ticket GEMM (dense sliding write window) ------
// 512 persistent blocks pull globally-ORDERED tickets: ticket = 64-row band x
// 8-strip col chunk, band-major. At any instant the chip writes ~5 consecutive
// bands densely (each band's 12.9MB C region covered in ~2us, ~330 active row
// streams << DRAM banks) -> fill-like DRAM write efficiency instead of 32K
// dribbling streams. Compute per ticket: wave w owns 2 strips; per n-step:
// 4 B-frag loads, 16 MFMA (swapped operands), 4 wide dwordx4 stores.
__global__ __launch_bounds__(256, 2) void gemm8_kernel(
    const ushort* __restrict__ A,       // emb bf16 [4096][128]
    const ushort* __restrict__ Btf,     // [786][16][64][8] bf16 frag-ordered
    float* __restrict__ C,
    unsigned int* __restrict__ cnt) {
  __shared__ unsigned int sT;

  int tid  = threadIdx.x;
  int lane = tid & 63;
  int wv   = tid >> 6;
  int lr   = lane & 15;
  int lg   = lane >> 4;

  for (;;) {
    __syncthreads();                    // all read previous sT before rewrite
    if (tid == 0) sT = atomicAdd(cnt, 1u);
    __syncthreads();
    unsigned int t = sT;
    if (t >= NTICK) break;

    int band = (int)(t / QCHUNKS);
    int q    = (int)(t % QCHUNKS);
    int R0   = band * 64;

    // A fragments for this band: rows R0 + rg*16 + lr (L2/L3-resident)
    const ushort* Ag = A + (size_t)R0 * EMBED;
    bf16x8 af[4][4];
#pragma unroll
    for (int rg = 0; rg < 4; ++rg)
#pragma unroll
      for (int kq = 0; kq < 4; ++kq)
        af[rg][kq] = *reinterpret_cast<const bf16x8*>(
            Ag + (rg * 16 + lr) * EMBED + kq * 32 + lg * 8);

#pragma unroll
    for (int si = 0; si < 2; ++si) {
      int s = q * 8 + wv * 2 + si;
      if (s >= NXT) continue;           // wave-uniform (only chunk 98 tail)
      const ushort* Bg = Btf + (size_t)s * 8192 + lane * 8;
      bool edge = (s == NXT - 1);
      int colb = s * 64 + lg * 4;

#pragma unroll
      for (int n = 0; n < 4; ++n) {
        bf16x8 b[4];
#pragma unroll
        for (int kq = 0; kq < 4; ++kq)
          b[kq] = *reinterpret_cast<const bf16x8*>(Bg + (kq * 4 + n) * 512);

        f32x4 acc[4];
#pragma unroll
        for (int rg = 0; rg < 4; ++rg) {
          f32x4 z = {0.f, 0.f, 0.f, 0.f};
          acc[rg] = z;
        }
#pragma unroll
        for (int kq = 0; kq < 4; ++kq)
#pragma unroll
          for (int rg = 0; rg < 4; ++rg)
            acc[rg] = __builtin_amdgcn_mfma_f32_16x16x32_bf16(
                b[kq], af[rg][kq], acc[rg], 0, 0, 0);

        int col = colb + n * 16;
        if (!edge) {
#pragma unroll
          for (int rg = 0; rg < 4; ++rg) {
            float* cp = C + (size_t)(R0 + rg * 16 + lr) * VOCAB + col;
            *reinterpret_cast<f32x4u*>(cp) = __builtin_bit_cast(f32x4u, acc[rg]);
          }
        } else {
#pragma unroll
          for (int rg = 0; rg < 4; ++rg) {
            float* cp = C + (size_t)(R0 + rg * 16 + lr) * VOCAB;
            if (col + 3 < VOCAB) {
              *reinterpret_cast<f32x4u*>(cp + col) = __builtin_bit_cast(f32x4u, acc[rg]);
            } else {
#pragma unroll
              for (int qq = 0; qq < 4; ++qq)
                if (col + qq < VOCAB) cp[col + qq] = acc[rg][qq];
            }
          }
        }
      }
    }
  }
}

// ---------------- Fallback GEMM (R2 style) if ws too small ----------------
#define FLDSP 132
__global__ __launch_bounds__(256, 4) void gemm_kernel(
    const __hip_bfloat16* __restrict__ A,
    const float* __restrict__ Bm,
    float* __restrict__ C) {
  __shared__ char BsRaw[64 * FLDSP * 2];
  int bid = blockIdx.x;
  int k8  = bid & 7;
  int j   = bid >> 3;
  int t   = j >> 5;
  int y   = j & 31;
  int x   = k8 + t * 8;
  if (x >= NXT) return;

  int tid  = threadIdx.x;
  int lane = tid & 63;
  int wv   = tid >> 6;
  int lr   = lane & 15;
  int lg   = lane >> 4;
  int r0   = wv * 32;

  const ushort* Ag = reinterpret_cast<const ushort*>(A) + (size_t)(y * BM) * EMBED;
  uint4 a_raw[2][4];
#pragma unroll
  for (int m = 0; m < 2; ++m)
#pragma unroll
    for (int kq = 0; kq < 4; ++kq)
      a_raw[m][kq] = *reinterpret_cast<const uint4*>(
          Ag + (r0 + m * 16 + lr) * EMBED + kq * 32 + lg * 8);

  int cbase = x * 64;
  bool edge = (x == NXT - 1);
  float4 bb[8];
#pragma unroll
  for (int i = 0; i < 8; ++i) {
    int c  = tid + i * 256;
    int e  = c >> 4;
    int v4 = (c & 15) << 2;
    int col = cbase + v4;
    if (!edge) {
      bb[i] = *reinterpret_cast<const float4*>(Bm + (size_t)e * VOCAB + col);
    } else {
      bb[i].x = (col + 0 < VOCAB) ? Bm[(size_t)e * VOCAB + col + 0] : 0.f;
      bb[i].y = (col + 1 < VOCAB) ? Bm[(size_t)e * VOCAB + col + 1] : 0.f;
      bb[i].z = (col + 2 < VOCAB) ? Bm[(size_t)e * VOCAB + col + 2] : 0.f;
      bb[i].w = (col + 3 < VOCAB) ? Bm[(size_t)e * VOCAB + col + 3] : 0.f;
    }
  }
#pragma unroll
  for (int i = 0; i < 8; ++i) {
    int c  = tid + i * 256;
    int e  = c >> 4;
    int v4 = (c & 15) << 2;
    float vals[4] = {bb[i].x, bb[i].y, bb[i].z, bb[i].w};
#pragma unroll
    for (int jj = 0; jj < 4; ++jj) {
      int v   = v4 + jj;
      int off = v * (FLDSP * 2) + ((e * 2) ^ ((v & 28) << 2));
      *reinterpret_cast<ushort*>(BsRaw + off) = f2bf(vals[jj]);
    }
  }
  __syncthreads();

  f32x4 acc[2][4] = {};
#pragma unroll
  for (int kq = 0; kq < 4; ++kq) {
    int ebyte = (kq * 32 + lg * 8) * 2;
    bf16x8 bfr[4];
#pragma unroll
    for (int n = 0; n < 4; ++n) {
      int v   = n * 16 + lr;
      int off = v * (FLDSP * 2) + (ebyte ^ ((v & 28) << 2));
      bfr[n] = *reinterpret_cast<const bf16x8*>(BsRaw + off);
    }
#pragma unroll
    for (int m = 0; m < 2; ++m) {
      bf16x8 af = __builtin_bit_cast(bf16x8, a_raw[m][kq]);
#pragma unroll
      for (int n = 0; n < 4; ++n)
        acc[m][n] = __builtin_amdgcn_mfma_f32_16x16x32_bf16(af, bfr[n], acc[m][n], 0, 0, 0);
    }
  }

  size_t crow0 = (size_t)y * BM + r0;
#pragma unroll
  for (int m = 0; m < 2; ++m) {
#pragma unroll
    for (int n = 0; n < 4; ++n) {
      int colc = cbase + n * 16 + lr;
      if (colc < VOCAB) {
        float* cp = C + (crow0 + m * 16 + lg * 4) * (size_t)VOCAB + colc;
#pragma unroll
        for (int q = 0; q < 4; ++q)
          cp[(size_t)q * VOCAB] = acc[m][n][q];
      }
    }
  }
}

extern "C" void kernel_launch(void* const* d_in, const int* in_sizes, int n_in,
                              void* d_out, int out_size, void* d_ws, size_t ws_size,
                              hipStream_t stream) {
  const int*   idx    = (const int*)d_in[0];
  const float* W_proj = (const float*)d_in[1];
  const float* W_pred = (const float*)d_in[2];
  float*       out    = (float*)d_out;

  __hip_bfloat16* emb = (__hip_bfloat16*)d_ws;                 // [0, 1MB)
  ushort* Btf = (ushort*)((char*)d_ws + (size_t)1048576);      // [1MB, ~13.9MB)
  unsigned int* cnt = (unsigned int*)((char*)d_ws + (size_t)14680064);  // @14MB
  const size_t needed = (size_t)14680064 + 64;

  embed_bag_kernel<<<BATCH / 4, 256, 0, stream>>>(idx, W_proj, emb);

  if (ws_size >= needed) {
    transpose_b_kernel<<<NXT, 256, 0, stream>>>(W_pred, Btf);
    hipMemsetAsync(cnt, 0, sizeof(unsigned int), stream);
    gemm8_kernel<<<512, 256, 0, stream>>>((const ushort*)emb, Btf, out, cnt);
  } else {
    int strips = (NXT + 7) / 8;
    int grid = 8 * strips * 32;
    gemm_kernel<<<grid, 256, 0, stream>>>(emb, W_pred, out);
  }
}